// Round 1
// baseline (260.497 us; speedup 1.0000x reference)
//
#include <hip/hip_runtime.h>
#include <hip/hip_bf16.h>
#include <math.h>

typedef short bf16x8 __attribute__((ext_vector_type(8)));
typedef float f32x4 __attribute__((ext_vector_type(4)));
typedef unsigned short u16;
typedef unsigned int u32;

#define BATCH 128
#define NE 256
#define NO 256
#define NT 32
#define NH 768
#define NP 256
#define INV_TEMP 14.285714285714285714f

__device__ __forceinline__ u16 f2bf(float f) {
    union { float f; u32 u; } v; v.f = f;
    u32 u = v.u;
    u += 0x7fffu + ((u >> 16) & 1u);   // round-to-nearest-even
    return (u16)(u >> 16);
}

// ---------------- weight transpose + convert: W[K][N] f32 -> WT[N][K] bf16 ----
__global__ void wconv_kernel(const float* __restrict__ W, u16* __restrict__ WT,
                             int K, int N) {
    int id = blockIdx.x * 256 + threadIdx.x;
    if (id >= K * N) return;
    int n = id / K, k = id - n * K;
    WT[id] = f2bf(W[(size_t)k * N + n]);
}

// ---------------- activation convert, optional gather ------------------------
// opinions: rows = B*O, src row = row.   entities: rows = B*T, src row = b*E + pairs[2*row]
__global__ void aconv_kernel(const float* __restrict__ A, const int* __restrict__ pairs,
                             u16* __restrict__ out, int nrows) {
    // each thread converts 8 elements; NH/8 = 96 chunks per row
    int gid = blockIdx.x * 256 + threadIdx.x;
    int total = nrows * (NH / 8);
    if (gid >= total) return;
    int row = gid / (NH / 8);
    int q = gid - row * (NH / 8);
    size_t srow;
    if (pairs) {
        int e = pairs[2 * row];
        int b = row >> 5;            // T = 32
        srow = (size_t)(b * NE + e);
    } else {
        srow = (size_t)row;
    }
    const float* p = A + srow * NH + q * 8;
    float4 a0 = *(const float4*)(p);
    float4 a1 = *(const float4*)(p + 4);
    u16 ua[8];
    ua[0] = f2bf(a0.x); ua[1] = f2bf(a0.y); ua[2] = f2bf(a0.z); ua[3] = f2bf(a0.w);
    ua[4] = f2bf(a1.x); ua[5] = f2bf(a1.y); ua[6] = f2bf(a1.z); ua[7] = f2bf(a1.w);
    *(uint4*)(out + (size_t)row * NH + q * 8) = *(uint4*)ua;
}

// ---------------- GEMM1: h = relu(A @ W1 + b1), A bf16 [M][768], W1T bf16 [768][768]
// tile 128x128, BK=32, 4 waves (2x2), each wave 64x64 = 4x4 frags of 16x16x32
__launch_bounds__(256)
__global__ void gemm1_kernel(const u16* __restrict__ A, const u16* __restrict__ WT,
                             const float* __restrict__ bias, u16* __restrict__ outH) {
    __shared__ u16 As[128][32];
    __shared__ u16 Bs[128][32];
    const int nt = blockIdx.x % (NH / 128);   // 6 col tiles
    const int mt = blockIdx.x / (NH / 128);
    const int tid = threadIdx.x;
    const int lane = tid & 63;
    const int w = tid >> 6;
    const int wm = w >> 1, wn = w & 1;

    const int srow = tid >> 1;     // staging: 2 threads per row, 16 bf16 each
    const int shalf = tid & 1;
    const u16* aptr = A + (size_t)(mt * 128 + srow) * NH + shalf * 16;
    const u16* bptr = WT + (size_t)(nt * 128 + srow) * NH + shalf * 16;

    f32x4 acc[4][4] = {};

    for (int kk = 0; kk < NH; kk += 32) {
        uint4 a0 = *(const uint4*)(aptr + kk);
        uint4 a1 = *(const uint4*)(aptr + kk + 8);
        uint4 b0 = *(const uint4*)(bptr + kk);
        uint4 b1 = *(const uint4*)(bptr + kk + 8);
        *(uint4*)&As[srow][shalf * 16 + 0] = a0;
        *(uint4*)&As[srow][shalf * 16 + 8] = a1;
        *(uint4*)&Bs[srow][shalf * 16 + 0] = b0;
        *(uint4*)&Bs[srow][shalf * 16 + 8] = b1;
        __syncthreads();
        const int kq = (lane >> 4) << 3;
        bf16x8 af[4], bfr[4];
        #pragma unroll
        for (int m = 0; m < 4; ++m)
            af[m] = *(const bf16x8*)&As[wm * 64 + m * 16 + (lane & 15)][kq];
        #pragma unroll
        for (int n = 0; n < 4; ++n)
            bfr[n] = *(const bf16x8*)&Bs[wn * 64 + n * 16 + (lane & 15)][kq];
        #pragma unroll
        for (int m = 0; m < 4; ++m)
            #pragma unroll
            for (int n = 0; n < 4; ++n)
                acc[m][n] = __builtin_amdgcn_mfma_f32_16x16x32_bf16(af[m], bfr[n], acc[m][n], 0, 0, 0);
        __syncthreads();
    }

    const int r0 = (lane >> 4) << 2;
    const int ccol0 = nt * 128 + wn * 64 + (lane & 15);
    const int crow0 = mt * 128 + wm * 64 + r0;
    #pragma unroll
    for (int n = 0; n < 4; ++n) {
        const float bv = bias[ccol0 + n * 16];
        #pragma unroll
        for (int m = 0; m < 4; ++m) {
            #pragma unroll
            for (int r = 0; r < 4; ++r) {
                float v = acc[m][n][r] + bv;
                v = fmaxf(v, 0.0f);
                outH[(size_t)(crow0 + m * 16 + r) * NH + ccol0 + n * 16] = f2bf(v);
            }
        }
    }
}

// ---------------- GEMM2 + L2 normalize: z = h @ W2 + b2; out = z/||z|| (bf16)
// tile 64x256 (full row in block), BK=32, 4 waves side by side in N
__launch_bounds__(256)
__global__ void gemm2norm_kernel(const u16* __restrict__ Hin, const u16* __restrict__ WT,
                                 const float* __restrict__ bias, u16* __restrict__ outZ) {
    __shared__ u16 As[64][32];
    __shared__ u16 Bs[256][32];
    __shared__ float zbuf[64][257];
    __shared__ float invn[64];
    const int mt = blockIdx.x;
    const int tid = threadIdx.x;
    const int lane = tid & 63;
    const int w = tid >> 6;

    const int arow = tid >> 2, aq = tid & 3;    // 4 threads per row, 8 bf16 each
    const u16* aptr = Hin + (size_t)(mt * 64 + arow) * NH + aq * 8;
    const u16* bptr = WT + (size_t)tid * NH;    // one thread per output col

    f32x4 acc[4][4] = {};

    for (int kk = 0; kk < NH; kk += 32) {
        uint4 av = *(const uint4*)(aptr + kk);
        uint4 b0 = *(const uint4*)(bptr + kk);
        uint4 b1 = *(const uint4*)(bptr + kk + 8);
        uint4 b2v = *(const uint4*)(bptr + kk + 16);
        uint4 b3 = *(const uint4*)(bptr + kk + 24);
        *(uint4*)&As[arow][aq * 8] = av;
        *(uint4*)&Bs[tid][0] = b0;
        *(uint4*)&Bs[tid][8] = b1;
        *(uint4*)&Bs[tid][16] = b2v;
        *(uint4*)&Bs[tid][24] = b3;
        __syncthreads();
        const int kq = (lane >> 4) << 3;
        bf16x8 af[4], bfr[4];
        #pragma unroll
        for (int m = 0; m < 4; ++m)
            af[m] = *(const bf16x8*)&As[m * 16 + (lane & 15)][kq];
        #pragma unroll
        for (int n = 0; n < 4; ++n)
            bfr[n] = *(const bf16x8*)&Bs[w * 64 + n * 16 + (lane & 15)][kq];
        #pragma unroll
        for (int m = 0; m < 4; ++m)
            #pragma unroll
            for (int n = 0; n < 4; ++n)
                acc[m][n] = __builtin_amdgcn_mfma_f32_16x16x32_bf16(af[m], bfr[n], acc[m][n], 0, 0, 0);
        __syncthreads();
    }

    const int r0 = (lane >> 4) << 2;
    const int cc = w * 64 + (lane & 15);
    #pragma unroll
    for (int n = 0; n < 4; ++n) {
        const float bv = bias[cc + n * 16];
        #pragma unroll
        for (int m = 0; m < 4; ++m)
            #pragma unroll
            for (int r = 0; r < 4; ++r)
                zbuf[m * 16 + r0 + r][cc + n * 16] = acc[m][n][r] + bv;
    }
    __syncthreads();
    if (tid < 64) {
        float s = 0.f;
        #pragma unroll 8
        for (int j = 0; j < NP; ++j) { float v = zbuf[tid][j]; s += v * v; }
        invn[tid] = 1.0f / fmaxf(sqrtf(s), 1e-12f);
    }
    __syncthreads();
    #pragma unroll
    for (int m = 0; m < 4; ++m) {
        #pragma unroll
        for (int r = 0; r < 4; ++r) {
            const int rr = m * 16 + r0 + r;
            const float iv = invn[rr];
            #pragma unroll
            for (int n = 0; n < 4; ++n)
                outZ[(size_t)(mt * 64 + rr) * NP + cc + n * 16] = f2bf(zbuf[rr][cc + n * 16] * iv);
        }
    }
}

// ---------------- score: per batch b, sim = epsel[b] @ opn[b]^T / TEMP, lse - pos
__launch_bounds__(256)
__global__ void score_kernel(const u16* __restrict__ epsel, const u16* __restrict__ opn,
                             const int* __restrict__ pairs, float* __restrict__ partials) {
    __shared__ u16 As[32][264];       // padded to break bank conflicts on frag reads
    __shared__ float simbuf[32][257];
    __shared__ float red[32];
    const int b = blockIdx.x;
    const int tid = threadIdx.x;
    const int lane = tid & 63;
    const int w = tid >> 6;
    {
        const int row = tid >> 3, q = tid & 7;   // 8 threads per row, 32 bf16 each
        const u16* p = epsel + ((size_t)(b * NT + row)) * NP + q * 32;
        #pragma unroll
        for (int i = 0; i < 4; ++i)
            *(uint4*)&As[row][q * 32 + i * 8] = *(const uint4*)(p + i * 8);
    }
    __syncthreads();
    f32x4 acc[2][4] = {};
    const u16* opb = opn + (size_t)b * NO * NP;
    const int kq = (lane >> 4) << 3;
    for (int kk = 0; kk < NP; kk += 32) {
        bf16x8 af[2], bfr[4];
        #pragma unroll
        for (int m = 0; m < 2; ++m)
            af[m] = *(const bf16x8*)&As[m * 16 + (lane & 15)][kk + kq];
        #pragma unroll
        for (int n = 0; n < 4; ++n)
            bfr[n] = *(const bf16x8*)(opb + (size_t)(w * 64 + n * 16 + (lane & 15)) * NP + kk + kq);
        #pragma unroll
        for (int m = 0; m < 2; ++m)
            #pragma unroll
            for (int n = 0; n < 4; ++n)
                acc[m][n] = __builtin_amdgcn_mfma_f32_16x16x32_bf16(af[m], bfr[n], acc[m][n], 0, 0, 0);
    }
    const int r0 = (lane >> 4) << 2;
    #pragma unroll
    for (int m = 0; m < 2; ++m)
        #pragma unroll
        for (int n = 0; n < 4; ++n)
            #pragma unroll
            for (int r = 0; r < 4; ++r)
                simbuf[m * 16 + r0 + r][w * 64 + n * 16 + (lane & 15)] = acc[m][n][r] * INV_TEMP;
    __syncthreads();
    if (tid < NT) {
        float mx = -1e30f;
        for (int j = 0; j < NO; ++j) mx = fmaxf(mx, simbuf[tid][j]);
        float s = 0.f;
        for (int j = 0; j < NO; ++j) s += expf(simbuf[tid][j] - mx);
        const float lse = mx + logf(s);
        const int o = pairs[(b * NT + tid) * 2 + 1];
        red[tid] = lse - simbuf[tid][o];
    }
    __syncthreads();
    if (tid == 0) {
        float s = 0.f;
        #pragma unroll
        for (int t = 0; t < NT; ++t) s += red[t];
        partials[b] = s;
    }
}

__global__ void reduce_kernel(const float* __restrict__ partials, float* __restrict__ out) {
    if (threadIdx.x == 0) {
        float tot = 0.f;
        for (int i = 0; i < BATCH; ++i) tot += partials[i];
        out[0] = tot / (float)(BATCH * NT);
    }
}

extern "C" void kernel_launch(void* const* d_in, const int* in_sizes, int n_in,
                              void* d_out, int out_size, void* d_ws, size_t ws_size,
                              hipStream_t stream) {
    const float* ent  = (const float*)d_in[0];
    const float* opi  = (const float*)d_in[1];
    const int*   prs  = (const int*)d_in[2];
    const float* eW1  = (const float*)d_in[3];
    const float* eb1  = (const float*)d_in[4];
    const float* eW2  = (const float*)d_in[5];
    const float* eb2  = (const float*)d_in[6];
    const float* oW1  = (const float*)d_in[7];
    const float* ob1  = (const float*)d_in[8];
    const float* oW2  = (const float*)d_in[9];
    const float* ob2  = (const float*)d_in[10];
    float* out = (float*)d_out;

    char* ws = (char*)d_ws;
    size_t off = 0;
    auto alloc = [&](size_t bytes) {
        void* p = ws + off;
        off += (bytes + 255) & ~(size_t)255;
        return p;
    };
    u16* oW1T = (u16*)alloc((size_t)NH * NH * 2);
    u16* eW1T = (u16*)alloc((size_t)NH * NH * 2);
    u16* oW2T = (u16*)alloc((size_t)NP * NH * 2);
    u16* eW2T = (u16*)alloc((size_t)NP * NH * 2);
    u16* A_op = (u16*)alloc((size_t)BATCH * NO * NH * 2);
    u16* A_en = (u16*)alloc((size_t)BATCH * NT * NH * 2);
    u16* h_op = (u16*)alloc((size_t)BATCH * NO * NH * 2);
    u16* h_en = (u16*)alloc((size_t)BATCH * NT * NH * 2);
    u16* op_n = (u16*)alloc((size_t)BATCH * NO * NP * 2);
    u16* ep_s = (u16*)alloc((size_t)BATCH * NT * NP * 2);
    float* partials = (float*)alloc(BATCH * sizeof(float));
    (void)ws_size; (void)in_sizes; (void)n_in; (void)out_size;

    // weights -> bf16 transposed
    wconv_kernel<<<(NH * NH + 255) / 256, 256, 0, stream>>>(oW1, oW1T, NH, NH);
    wconv_kernel<<<(NH * NH + 255) / 256, 256, 0, stream>>>(eW1, eW1T, NH, NH);
    wconv_kernel<<<(NH * NP + 255) / 256, 256, 0, stream>>>(oW2, oW2T, NH, NP);
    wconv_kernel<<<(NH * NP + 255) / 256, 256, 0, stream>>>(eW2, eW2T, NH, NP);

    // activations -> bf16 (entities: gather only selected rows)
    {
        int nrows = BATCH * NO;
        int total = nrows * (NH / 8);
        aconv_kernel<<<(total + 255) / 256, 256, 0, stream>>>(opi, nullptr, A_op, nrows);
    }
    {
        int nrows = BATCH * NT;
        int total = nrows * (NH / 8);
        aconv_kernel<<<(total + 255) / 256, 256, 0, stream>>>(ent, prs, A_en, nrows);
    }

    // encoder layer 1 (relu)
    gemm1_kernel<<<(BATCH * NO / 128) * (NH / 128), 256, 0, stream>>>(A_op, oW1T, ob1, h_op);
    gemm1_kernel<<<(BATCH * NT / 128) * (NH / 128), 256, 0, stream>>>(A_en, eW1T, eb1, h_en);

    // encoder layer 2 + normalize
    gemm2norm_kernel<<<BATCH * NO / 64, 256, 0, stream>>>(h_op, oW2T, ob2, op_n);
    gemm2norm_kernel<<<BATCH * NT / 64, 256, 0, stream>>>(h_en, eW2T, eb2, ep_s);

    // similarity rows + InfoNCE partials
    score_kernel<<<BATCH, 256, 0, stream>>>(ep_s, op_n, prs, partials);
    reduce_kernel<<<1, 64, 0, stream>>>(partials, out);
}

// Round 2
// 192.220 us; speedup vs baseline: 1.3552x; 1.3552x over previous
//
#include <hip/hip_runtime.h>
#include <hip/hip_bf16.h>
#include <math.h>

typedef short bf16x8 __attribute__((ext_vector_type(8)));
typedef float f32x4 __attribute__((ext_vector_type(4)));
typedef unsigned short u16;
typedef unsigned int u32;

#define BATCH 128
#define NE 256
#define NO 256
#define NT 32
#define NH 768
#define NP 256
#define INV_TEMP 14.285714285714285714f

__device__ __forceinline__ u16 f2bf(float f) {
    union { float f; u32 u; } v; v.f = f;
    u32 u = v.u;
    u += 0x7fffu + ((u >> 16) & 1u);   // round-to-nearest-even
    return (u16)(u >> 16);
}

__device__ __forceinline__ void gload16(const void* g, void* l) {
    __builtin_amdgcn_global_load_lds(
        (const __attribute__((address_space(1))) unsigned int*)g,
        (__attribute__((address_space(3))) unsigned int*)l,
        16, 0, 0);
}

// ---------------- weight transpose + convert: W[K][N] f32 -> WT[N][K] bf16 ----
__global__ void wconv_kernel(const float* __restrict__ W, u16* __restrict__ WT,
                             int K, int N) {
    int id = blockIdx.x * 256 + threadIdx.x;
    if (id >= K * N) return;
    int n = id / K, k = id - n * K;
    WT[id] = f2bf(W[(size_t)k * N + n]);
}

// ---------------- activation convert, optional gather ------------------------
__global__ void aconv_kernel(const float* __restrict__ A, const int* __restrict__ pairs,
                             u16* __restrict__ out, int nrows) {
    int gid = blockIdx.x * 256 + threadIdx.x;
    int total = nrows * (NH / 8);
    if (gid >= total) return;
    int row = gid / (NH / 8);
    int q = gid - row * (NH / 8);
    size_t srow;
    if (pairs) {
        int e = pairs[2 * row];
        int b = row >> 5;            // T = 32
        srow = (size_t)(b * NE + e);
    } else {
        srow = (size_t)row;
    }
    const float* p = A + srow * NH + q * 8;
    float4 a0 = *(const float4*)(p);
    float4 a1 = *(const float4*)(p + 4);
    u16 ua[8];
    ua[0] = f2bf(a0.x); ua[1] = f2bf(a0.y); ua[2] = f2bf(a0.z); ua[3] = f2bf(a0.w);
    ua[4] = f2bf(a1.x); ua[5] = f2bf(a1.y); ua[6] = f2bf(a1.z); ua[7] = f2bf(a1.w);
    *(uint4*)(out + (size_t)row * NH + q * 8) = *(uint4*)ua;
}

// ---------------- GEMM1: h = relu(A @ W1 + b1) -------------------------------
// 128x128 tile, BK=64, 4 waves (2x2), global_load_lds staging, XOR-swizzled LDS.
// LDS rows are 128B; swizzle c' = c ^ ((row&7)<<4) applied on BOTH the global
// source address (inverse) and the ds_read address (involution, rule #21).
__launch_bounds__(256)
__global__ void gemm1_kernel(const u16* __restrict__ A, const u16* __restrict__ WT,
                             const float* __restrict__ bias, u16* __restrict__ outH) {
    __shared__ u16 As[128 * 64];
    __shared__ u16 Bs[128 * 64];
    // XCD-aware bijective swizzle (gridDim.x % 8 == 0 guaranteed by launch)
    const int cpx = gridDim.x >> 3;
    const int wg = (blockIdx.x & 7) * cpx + (blockIdx.x >> 3);
    const int mt = wg / (NH / 128);
    const int nt = wg % (NH / 128);
    const int tid = threadIdx.x;
    const int lane = tid & 63;
    const int w = tid >> 6;
    const int wm = w >> 1, wn = w & 1;

    // staging geometry: per instr i, this lane covers LDS row i*32 + w*8 + lane/8,
    // byte col (lane&7)*16 (linear). Global source col gets the inverse swizzle.
    const int srow = w * 8 + (lane >> 3);
    const int sswz = ((lane & 7) * 16) ^ ((lane >> 3) << 4);
    const u16* ag = A + (size_t)(mt * 128) * NH;
    const u16* bg = WT + (size_t)(nt * 128) * NH;

    f32x4 acc[4][4] = {};

    for (int kk = 0; kk < NH; kk += 64) {
        #pragma unroll
        for (int i = 0; i < 4; ++i) {
            const int row = i * 32 + srow;
            gload16((const char*)(ag + (size_t)row * NH + kk) + sswz,
                    (char*)As + i * 4096 + w * 1024);
            gload16((const char*)(bg + (size_t)row * NH + kk) + sswz,
                    (char*)Bs + i * 4096 + w * 1024);
        }
        __syncthreads();
        bf16x8 af[4][2], bfr[4][2];
        const int cq = (lane >> 4) << 4;      // 16B frag byte col within 32-elem slice
        #pragma unroll
        for (int m = 0; m < 4; ++m) {
            const int row = wm * 64 + m * 16 + (lane & 15);
            const int rs = (row & 7) << 4;
            #pragma unroll
            for (int ks = 0; ks < 2; ++ks)
                af[m][ks] = *(const bf16x8*)((const char*)As + row * 128 + ((ks * 64 + cq) ^ rs));
        }
        #pragma unroll
        for (int n = 0; n < 4; ++n) {
            const int row = wn * 64 + n * 16 + (lane & 15);
            const int rs = (row & 7) << 4;
            #pragma unroll
            for (int ks = 0; ks < 2; ++ks)
                bfr[n][ks] = *(const bf16x8*)((const char*)Bs + row * 128 + ((ks * 64 + cq) ^ rs));
        }
        #pragma unroll
        for (int ks = 0; ks < 2; ++ks)
            #pragma unroll
            for (int m = 0; m < 4; ++m)
                #pragma unroll
                for (int n = 0; n < 4; ++n)
                    acc[m][n] = __builtin_amdgcn_mfma_f32_16x16x32_bf16(af[m][ks], bfr[n][ks], acc[m][n], 0, 0, 0);
        __syncthreads();
    }

    const int r0 = (lane >> 4) << 2;
    const int ccol0 = nt * 128 + wn * 64 + (lane & 15);
    const int crow0 = mt * 128 + wm * 64 + r0;
    #pragma unroll
    for (int n = 0; n < 4; ++n) {
        const float bv = bias[ccol0 + n * 16];
        #pragma unroll
        for (int m = 0; m < 4; ++m) {
            #pragma unroll
            for (int r = 0; r < 4; ++r) {
                float v = acc[m][n][r] + bv;
                v = fmaxf(v, 0.0f);
                outH[(size_t)(crow0 + m * 16 + r) * NH + ccol0 + n * 16] = f2bf(v);
            }
        }
    }
}

// ---------------- GEMM2 + L2 normalize: z = h @ W2 + b2; out = z/||z|| -------
// tile 64x256 (full output row in block), BK=64, 4 waves side-by-side in N.
// Norm computed from accumulators: shfl_xor row-reduce + tiny cross-wave LDS.
__launch_bounds__(256)
__global__ void gemm2norm_kernel(const u16* __restrict__ Hin, const u16* __restrict__ WT,
                                 const float* __restrict__ bias, u16* __restrict__ outZ) {
    __shared__ u16 As[64 * 64];        // 8 KB
    __shared__ u16 Bs[256 * 64];       // 32 KB
    __shared__ float nsum[4][64];
    const int mt = blockIdx.x;
    const int tid = threadIdx.x;
    const int lane = tid & 63;
    const int w = tid >> 6;

    const int srow = w * 8 + (lane >> 3);
    const int sswz = ((lane & 7) * 16) ^ ((lane >> 3) << 4);
    const u16* ag = Hin + (size_t)(mt * 64) * NH;

    f32x4 acc[4][4] = {};

    for (int kk = 0; kk < NH; kk += 64) {
        #pragma unroll
        for (int i = 0; i < 2; ++i) {
            const int row = i * 32 + srow;
            gload16((const char*)(ag + (size_t)row * NH + kk) + sswz,
                    (char*)As + i * 4096 + w * 1024);
        }
        #pragma unroll
        for (int i = 0; i < 8; ++i) {
            const int row = i * 32 + srow;
            gload16((const char*)(WT + (size_t)row * NH + kk) + sswz,
                    (char*)Bs + i * 4096 + w * 1024);
        }
        __syncthreads();
        bf16x8 af[4][2], bfr[4][2];
        const int cq = (lane >> 4) << 4;
        #pragma unroll
        for (int m = 0; m < 4; ++m) {
            const int row = m * 16 + (lane & 15);
            const int rs = (row & 7) << 4;
            #pragma unroll
            for (int ks = 0; ks < 2; ++ks)
                af[m][ks] = *(const bf16x8*)((const char*)As + row * 128 + ((ks * 64 + cq) ^ rs));
        }
        #pragma unroll
        for (int n = 0; n < 4; ++n) {
            const int row = w * 64 + n * 16 + (lane & 15);
            const int rs = (row & 7) << 4;
            #pragma unroll
            for (int ks = 0; ks < 2; ++ks)
                bfr[n][ks] = *(const bf16x8*)((const char*)Bs + row * 128 + ((ks * 64 + cq) ^ rs));
        }
        #pragma unroll
        for (int ks = 0; ks < 2; ++ks)
            #pragma unroll
            for (int m = 0; m < 4; ++m)
                #pragma unroll
                for (int n = 0; n < 4; ++n)
                    acc[m][n] = __builtin_amdgcn_mfma_f32_16x16x32_bf16(af[m][ks], bfr[n][ks], acc[m][n], 0, 0, 0);
        __syncthreads();
    }

    // bias
    const int cc = w * 64 + (lane & 15);
    #pragma unroll
    for (int n = 0; n < 4; ++n) {
        const float bv = bias[cc + n * 16];
        #pragma unroll
        for (int m = 0; m < 4; ++m)
            #pragma unroll
            for (int r = 0; r < 4; ++r)
                acc[m][n][r] += bv;
    }
    // per-row sum of squares: wave-local partial over its 64 cols
    float rs[4][4];
    #pragma unroll
    for (int m = 0; m < 4; ++m)
        #pragma unroll
        for (int r = 0; r < 4; ++r) {
            float s = 0.f;
            #pragma unroll
            for (int n = 0; n < 4; ++n) s += acc[m][n][r] * acc[m][n][r];
            rs[m][r] = s;
        }
    #pragma unroll
    for (int mask = 1; mask <= 8; mask <<= 1)
        #pragma unroll
        for (int m = 0; m < 4; ++m)
            #pragma unroll
            for (int r = 0; r < 4; ++r)
                rs[m][r] += __shfl_xor(rs[m][r], mask);
    const int r0 = (lane >> 4) << 2;
    if ((lane & 15) == 0) {
        #pragma unroll
        for (int m = 0; m < 4; ++m)
            #pragma unroll
            for (int r = 0; r < 4; ++r)
                nsum[w][m * 16 + r0 + r] = rs[m][r];
    }
    __syncthreads();
    #pragma unroll
    for (int m = 0; m < 4; ++m) {
        #pragma unroll
        for (int r = 0; r < 4; ++r) {
            const int row = m * 16 + r0 + r;
            const float tot = nsum[0][row] + nsum[1][row] + nsum[2][row] + nsum[3][row];
            const float inv = 1.0f / fmaxf(sqrtf(tot), 1e-12f);
            #pragma unroll
            for (int n = 0; n < 4; ++n)
                outZ[(size_t)(mt * 64 + row) * NP + cc + n * 16] = f2bf(acc[m][n][r] * inv);
        }
    }
}

// ---------------- score: per batch b, sim = epsel[b] @ opn[b]^T / TEMP, lse - pos
__launch_bounds__(256)
__global__ void score_kernel(const u16* __restrict__ epsel, const u16* __restrict__ opn,
                             const int* __restrict__ pairs, float* __restrict__ partials) {
    __shared__ u16 As[32][264];
    __shared__ float simbuf[32][257];
    __shared__ float red[32];
    const int b = blockIdx.x;
    const int tid = threadIdx.x;
    const int lane = tid & 63;
    const int w = tid >> 6;
    {
        const int row = tid >> 3, q = tid & 7;
        const u16* p = epsel + ((size_t)(b * NT + row)) * NP + q * 32;
        #pragma unroll
        for (int i = 0; i < 4; ++i)
            *(uint4*)&As[row][q * 32 + i * 8] = *(const uint4*)(p + i * 8);
    }
    __syncthreads();
    f32x4 acc[2][4] = {};
    const u16* opb = opn + (size_t)b * NO * NP;
    const int kq = (lane >> 4) << 3;
    for (int kk = 0; kk < NP; kk += 32) {
        bf16x8 af[2], bfr[4];
        #pragma unroll
        for (int m = 0; m < 2; ++m)
            af[m] = *(const bf16x8*)&As[m * 16 + (lane & 15)][kk + kq];
        #pragma unroll
        for (int n = 0; n < 4; ++n)
            bfr[n] = *(const bf16x8*)(opb + (size_t)(w * 64 + n * 16 + (lane & 15)) * NP + kk + kq);
        #pragma unroll
        for (int m = 0; m < 2; ++m)
            #pragma unroll
            for (int n = 0; n < 4; ++n)
                acc[m][n] = __builtin_amdgcn_mfma_f32_16x16x32_bf16(af[m], bfr[n], acc[m][n], 0, 0, 0);
    }
    const int r0 = (lane >> 4) << 2;
    #pragma unroll
    for (int m = 0; m < 2; ++m)
        #pragma unroll
        for (int n = 0; n < 4; ++n)
            #pragma unroll
            for (int r = 0; r < 4; ++r)
                simbuf[m * 16 + r0 + r][w * 64 + n * 16 + (lane & 15)] = acc[m][n][r] * INV_TEMP;
    __syncthreads();
    if (tid < NT) {
        float mx = -1e30f;
        for (int j = 0; j < NO; ++j) mx = fmaxf(mx, simbuf[tid][j]);
        float s = 0.f;
        for (int j = 0; j < NO; ++j) s += expf(simbuf[tid][j] - mx);
        const float lse = mx + logf(s);
        const int o = pairs[(b * NT + tid) * 2 + 1];
        red[tid] = lse - simbuf[tid][o];
    }
    __syncthreads();
    if (tid == 0) {
        float s = 0.f;
        #pragma unroll
        for (int t = 0; t < NT; ++t) s += red[t];
        partials[b] = s;
    }
}

__global__ void reduce_kernel(const float* __restrict__ partials, float* __restrict__ out) {
    if (threadIdx.x == 0) {
        float tot = 0.f;
        for (int i = 0; i < BATCH; ++i) tot += partials[i];
        out[0] = tot / (float)(BATCH * NT);
    }
}

extern "C" void kernel_launch(void* const* d_in, const int* in_sizes, int n_in,
                              void* d_out, int out_size, void* d_ws, size_t ws_size,
                              hipStream_t stream) {
    const float* ent  = (const float*)d_in[0];
    const float* opi  = (const float*)d_in[1];
    const int*   prs  = (const int*)d_in[2];
    const float* eW1  = (const float*)d_in[3];
    const float* eb1  = (const float*)d_in[4];
    const float* eW2  = (const float*)d_in[5];
    const float* eb2  = (const float*)d_in[6];
    const float* oW1  = (const float*)d_in[7];
    const float* ob1  = (const float*)d_in[8];
    const float* oW2  = (const float*)d_in[9];
    const float* ob2  = (const float*)d_in[10];
    float* out = (float*)d_out;

    char* ws = (char*)d_ws;
    size_t off = 0;
    auto alloc = [&](size_t bytes) {
        void* p = ws + off;
        off += (bytes + 255) & ~(size_t)255;
        return p;
    };
    u16* oW1T = (u16*)alloc((size_t)NH * NH * 2);
    u16* eW1T = (u16*)alloc((size_t)NH * NH * 2);
    u16* oW2T = (u16*)alloc((size_t)NP * NH * 2);
    u16* eW2T = (u16*)alloc((size_t)NP * NH * 2);
    u16* A_op = (u16*)alloc((size_t)BATCH * NO * NH * 2);
    u16* A_en = (u16*)alloc((size_t)BATCH * NT * NH * 2);
    u16* h_op = (u16*)alloc((size_t)BATCH * NO * NH * 2);
    u16* h_en = (u16*)alloc((size_t)BATCH * NT * NH * 2);
    u16* op_n = (u16*)alloc((size_t)BATCH * NO * NP * 2);
    u16* ep_s = (u16*)alloc((size_t)BATCH * NT * NP * 2);
    float* partials = (float*)alloc(BATCH * sizeof(float));
    (void)ws_size; (void)in_sizes; (void)n_in; (void)out_size;

    // weights -> bf16 transposed
    wconv_kernel<<<(NH * NH + 255) / 256, 256, 0, stream>>>(oW1, oW1T, NH, NH);
    wconv_kernel<<<(NH * NH + 255) / 256, 256, 0, stream>>>(eW1, eW1T, NH, NH);
    wconv_kernel<<<(NH * NP + 255) / 256, 256, 0, stream>>>(oW2, oW2T, NH, NP);
    wconv_kernel<<<(NH * NP + 255) / 256, 256, 0, stream>>>(eW2, eW2T, NH, NP);

    // activations -> bf16 (entities: gather only selected rows)
    {
        int nrows = BATCH * NO;
        int total = nrows * (NH / 8);
        aconv_kernel<<<(total + 255) / 256, 256, 0, stream>>>(opi, nullptr, A_op, nrows);
    }
    {
        int nrows = BATCH * NT;
        int total = nrows * (NH / 8);
        aconv_kernel<<<(total + 255) / 256, 256, 0, stream>>>(ent, prs, A_en, nrows);
    }

    // encoder layer 1 (relu); grids are 1536 and 192 — both % 8 == 0 (XCD swizzle)
    gemm1_kernel<<<(BATCH * NO / 128) * (NH / 128), 256, 0, stream>>>(A_op, oW1T, ob1, h_op);
    gemm1_kernel<<<(BATCH * NT / 128) * (NH / 128), 256, 0, stream>>>(A_en, eW1T, eb1, h_en);

    // encoder layer 2 + normalize
    gemm2norm_kernel<<<BATCH * NO / 64, 256, 0, stream>>>(h_op, oW2T, ob2, op_n);
    gemm2norm_kernel<<<BATCH * NT / 64, 256, 0, stream>>>(h_en, eW2T, eb2, ep_s);

    // similarity rows + InfoNCE partials
    score_kernel<<<BATCH, 256, 0, stream>>>(ep_s, op_n, prs, partials);
    reduce_kernel<<<1, 64, 0, stream>>>(partials, out);
}